// Round 3
// baseline (75.251 us; speedup 1.0000x reference)
//
#include <hip/hip_runtime.h>

// Problem constants (B=131072 rows, C=64 cols)
#define NROWS 131072
#define NCOLS 64
#define NBLK_A 512
#define THREADS_A 1024
#define WAVES_A 16
#define ROWS_PER_WAVE 16     // 512 blocks * 16 waves * 16 rows = 131072
#define PK_CELLS 4096        // packed u16-pair cells per block (2048 S + 2048 P)
#define NBLK_Z 64
#define NGRP 16              // kernZ: 64*1024 threads = 16 groups x 4096 cells

// Workspace layout:
//   [0]      u32 cnt           (cleared by kernA block 0 every call)
//   [64]     double fredD[64]
//   [1024]   float  pkF[512]   (per-block focal sums)
//   [8192]   u32    red[16][2][64][64]  (512 KB)
//   [532480] u32    pk[512][4096]       (8 MB)

// -------- Kernel A: fused focal loss + Gram (S = t^T t, P = v^T w) --------
// Lane l: cols c4=4*(l&15)..+3, rows r0+h+4q (h=l>>4, q=0..3) via float4.
// 16-bit column masks built with disjoint bits (4q+h), OR-combined via
// shfl_xor(16|32); lane owns column jc=c4+h. Waves w and w+8 merge masks
// (rows interleave; Gram is row-permutation-invariant) so only waves 0-7
// run the 64-iter readlane/popc Gram on 32-bit masks. Byte-packed counts
// (<=32) -> u16-pair LDS atomics (block sum <= 8*32=256) -> packed partial.
template<bool ATOMIC_FLUSH>
__global__ __launch_bounds__(THREADS_A, 8)
void kernA(const float* __restrict__ in, const float* __restrict__ tg,
           const float* __restrict__ pw,
           unsigned* __restrict__ pk, float* __restrict__ pkF,
           unsigned* __restrict__ cnt,
           unsigned* __restrict__ gS, unsigned* __restrict__ gP) {
    __shared__ unsigned ldsSP[PK_CELLS];   // [0..2047]=S packed, [2048..4095]=P
    __shared__ unsigned ldsX[WAVES_A * 64];
    __shared__ float fpart[WAVES_A];
    const int tid = threadIdx.x;
    if (!ATOMIC_FLUSH && blockIdx.x == 0 && tid == 0) atomicExch(cnt, 0u);
#pragma unroll
    for (int k = tid; k < PK_CELLS; k += THREADS_A) ldsSP[k] = 0u;
    __syncthreads();

    const int lane = tid & 63;
    const int wv = tid >> 6;                 // 0..15
    const int h = lane >> 4;                 // row phase 0..3
    const int c4 = (lane & 15) * 4;
    const int jc = c4 + h;                   // this lane's owned column
    const int row0 = blockIdx.x * (WAVES_A * ROWS_PER_WAVE) + wv * ROWS_PER_WAVE;

    const float4 pw4 = *reinterpret_cast<const float4*>(pw + c4);
    const float4* inp = reinterpret_cast<const float4*>(in + (size_t)(row0 + h) * NCOLS + c4);
    const float4* tgp = reinterpret_cast<const float4*>(tg + (size_t)(row0 + h) * NCOLS + c4);
    const unsigned hbit = 1u << h;

    float fsum = 0.f;
    unsigned m4[4] = {0u, 0u, 0u, 0u};
    unsigned v4[4] = {0u, 0u, 0u, 0u};

    auto elem = [&](float x, float t, float pwc, unsigned hq, unsigned& mk, unsigned& vk) {
        float ax = fabsf(x);
        float e = __expf(-ax);               // exp(-|x|)
        float L = __logf(1.f + e);           // log1p(exp(-|x|)), stable
        float inv = 1.f / (1.f + e);         // sigmoid(|x|)
        float qq = e * inv;                  // 1 - sigmoid(|x|)
        bool tb = t > 0.5f;
        bool pb = x >= 0.f;
        float w = (tb == pb) ? qq : inv;     // 1 - p_t
        float bce = tb ? pwc * (L + fmaxf(-x, 0.f)) : (L + fmaxf(x, 0.f));
        fsum += w * w * bce;
        mk |= tb ? hq : 0u;
        vk |= (tb && pb) ? hq : 0u;
    };

#pragma unroll
    for (int q = 0; q < 4; ++q) {            // rows r0 + h + 4q
        const float4 xv = inp[(size_t)q * 64];   // stride 4 rows = 64 float4
        const float4 tv = tgp[(size_t)q * 64];
        const unsigned hq = hbit << (4 * q); // disjoint bit 4q+h
        elem(xv.x, tv.x, pw4.x, hq, m4[0], v4[0]);
        elem(xv.y, tv.y, pw4.y, hq, m4[1], v4[1]);
        elem(xv.z, tv.z, pw4.z, hq, m4[2], v4[2]);
        elem(xv.w, tv.w, pw4.w, hq, m4[3], v4[3]);
    }

    // OR-combine the 4 row-phases; bit b = row r0+b for that column
#pragma unroll
    for (int k = 0; k < 4; ++k) {
        m4[k] |= __shfl_xor(m4[k], 16, 64);
        m4[k] |= __shfl_xor(m4[k], 32, 64);
        v4[k] |= __shfl_xor(v4[k], 16, 64);
        v4[k] |= __shfl_xor(v4[k], 32, 64);
    }
    // lane keeps the mask for its column jc = c4 + h (compile-time selects)
    const unsigned m = (h & 2) ? ((h & 1) ? m4[3] : m4[2]) : ((h & 1) ? m4[1] : m4[0]);
    const unsigned v = (h & 2) ? ((h & 1) ? v4[3] : v4[2]) : ((h & 1) ? v4[1] : v4[0]);

    // publish 16-bit masks for pair-merge; focal wave reduce
    ldsX[wv * 64 + jc] = (m & 0xFFFFu) | (v << 16);
#pragma unroll
    for (int off = 32; off; off >>= 1) fsum += __shfl_down(fsum, off, 64);
    if (lane == 0) fpart[wv] = fsum;
    __syncthreads();

    if (wv < 8) {
        const unsigned xo = ldsX[(wv + 8) * 64 + jc];
        const unsigned m32 = (m & 0xFFFFu) | (xo << 16);
        const unsigned v32 = v | (xo & 0xffff0000u);
        const unsigned wm32 = m32 & ~v32;    // t=1 & pred=0
#pragma unroll
        for (int k = 0; k < 16; ++k) {
            unsigned aS = 0u, aP = 0u;
#pragma unroll
            for (int b = 0; b < 4; ++b) {
                const int ri = (b << 4) | k; // lane owning column a = 4k+b
                unsigned mi = (unsigned)__builtin_amdgcn_readlane((int)m32, ri);
                unsigned vi = (unsigned)__builtin_amdgcn_readlane((int)v32, ri);
                aS += (unsigned)__popc(mi & m32) << (8 * b);   // S[4k+b][jc]
                aP += (unsigned)__popc(vi & wm32) << (8 * b);  // P[4k+b][jc]
            }
            atomicAdd(&ldsSP[(2 * k + 0) * 64 + jc],
                      (aS & 0xFFu) | (((aS >> 8) & 0xFFu) << 16));
            atomicAdd(&ldsSP[(2 * k + 1) * 64 + jc],
                      ((aS >> 16) & 0xFFu) | ((aS >> 24) << 16));
            atomicAdd(&ldsSP[2048 + (2 * k + 0) * 64 + jc],
                      (aP & 0xFFu) | (((aP >> 8) & 0xFFu) << 16));
            atomicAdd(&ldsSP[2048 + (2 * k + 1) * 64 + jc],
                      ((aP >> 16) & 0xFFu) | ((aP >> 24) << 16));
        }
    } else if (tid == 15 * 64) {             // an otherwise-idle wave sums focal
        float tot = 0.f;
#pragma unroll
        for (int k = 0; k < WAVES_A; ++k) tot += fpart[k];
        pkF[blockIdx.x] = tot;
    }
    __syncthreads();

    if (!ATOMIC_FLUSH) {
        // 4096 u32 = 1024 uint4 = one per thread, coalesced
        reinterpret_cast<uint4*>(pk + (size_t)blockIdx.x * PK_CELLS)[tid] =
            reinterpret_cast<const uint4*>(ldsSP)[tid];
    } else {
        for (int k = tid; k < 2048; k += THREADS_A) {
            const int wrd = k >> 6, j = k & 63;
            const int i0 = 2 * wrd;          // word w -> rows 2w, 2w+1
            unsigned s = ldsSP[k], p = ldsSP[2048 + k];
            atomicAdd(&gS[i0 * 64 + j], s & 0xFFFFu);
            atomicAdd(&gS[(i0 + 1) * 64 + j], s >> 16);
            atomicAdd(&gP[i0 * 64 + j], p & 0xFFFFu);
            atomicAdd(&gP[(i0 + 1) * 64 + j], p >> 16);
        }
    }
}

// -------- Kernel Z: fused reduce + penalty + finalize (last-block pattern) ----
__global__ __launch_bounds__(1024)
void kernZ(const unsigned* __restrict__ pk, const float* __restrict__ pkF,
           unsigned* __restrict__ red, double* __restrict__ fredD,
           unsigned* __restrict__ cnt, float* __restrict__ out) {
    const int tid = threadIdx.x;
    const int t = blockIdx.x * 1024 + tid;   // 0..65535 = 16 grps x 4096 cells
    const int grp = t >> 12;
    const int pc = t & 4095;
    unsigned lo = 0u, hi = 0u;
    const unsigned* p = pk + (size_t)(grp * 32) * PK_CELLS + pc;
#pragma unroll 8
    for (int b = 0; b < 32; ++b) {
        unsigned w = p[(size_t)b * PK_CELLS];
        lo += w & 0xFFFFu;
        hi += w >> 16;
    }
    const int mat = pc >> 11;                // 0=S, 1=P
    const int e = pc & 2047;
    const int i0 = (e >> 6) * 2;             // word -> rows i0, i0+1
    const int j = e & 63;
    unsigned* o = red + (((size_t)grp * 2 + mat) * 64 + i0) * 64 + j;
    o[0] = lo;
    o[64] = hi;
    if (tid == 0) {
        double fs = 0.0;
        const float* f = pkF + blockIdx.x * 8;
#pragma unroll
        for (int k = 0; k < 8; ++k) fs += (double)f[k];
        fredD[blockIdx.x] = fs;
    }
    __threadfence();
    __shared__ int isLast;
    if (tid == 0) isLast = (atomicAdd(cnt, 1u) == NBLK_Z - 1) ? 1 : 0;
    __syncthreads();
    if (!isLast) return;
    __threadfence();                         // acquire: invalidate stale cache

    double pend = 0.0;
#pragma unroll
    for (int kk = 0; kk < 4; ++kk) {
        const int c = tid + kk * 1024;       // cell (i,j), i=c>>6, j=c&63
        unsigned S = 0u, P = 0u;
#pragma unroll
        for (int g = 0; g < NGRP; ++g) {
            S += red[((size_t)g * 2 + 0) * 4096 + c];
            P += red[((size_t)g * 2 + 1) * 4096 + c];
        }
        const int i = c >> 6, j2 = c & 63;
        const float corr = (float)S * (1.0f / (float)NROWS);
        // penalty_total = 2 * sum A_ij P_ij, A = 0.5*corr thresholded => corr*P
        if (i != j2 && corr > 0.3f) pend += (double)corr * (double)P;
    }
#pragma unroll
    for (int off = 32; off; off >>= 1) pend += __shfl_down(pend, off, 64);
    __shared__ double wvred[16];
    const int lane = tid & 63, wv = tid >> 6;
    if (lane == 0) wvred[wv] = pend;
    __syncthreads();
    if (tid < 64) {
        double tot = (tid < 16 ? wvred[tid] : 0.0) + fredD[tid];
#pragma unroll
        for (int off = 32; off; off >>= 1) tot += __shfl_down(tot, off, 64);
        if (tid == 0) out[0] = (float)(tot * (1.0 / (double)((size_t)NROWS * NCOLS)));
    }
}

// -------- Fallback finalize (atomic path): one block does everything --------
__global__ void kernW(const unsigned* __restrict__ gS, const unsigned* __restrict__ gP,
                      const float* __restrict__ pkF, float* __restrict__ out) {
    const int tid = threadIdx.x;
    double acc = 0.0;
#pragma unroll
    for (int kk = 0; kk < 4; ++kk) {
        const int c = tid + kk * 1024;
        unsigned S = gS[c], P = gP[c];
        const int i = c >> 6, j = c & 63;
        const float corr = (float)S * (1.0f / (float)NROWS);
        if (i != j && corr > 0.3f) acc += (double)corr * (double)P;
    }
    if (tid < NBLK_A) acc += (double)pkF[tid];
#pragma unroll
    for (int off = 32; off; off >>= 1) acc += __shfl_down(acc, off, 64);
    __shared__ double wvred[16];
    const int lane = tid & 63, wv = tid >> 6;
    if (lane == 0) wvred[wv] = acc;
    __syncthreads();
    if (tid < 16) {
        double tot = wvred[tid];
#pragma unroll
        for (int off = 8; off; off >>= 1) tot += __shfl_down(tot, off, 64);
        if (tid == 0) out[0] = (float)(tot * (1.0 / (double)((size_t)NROWS * NCOLS)));
    }
}

extern "C" void kernel_launch(void* const* d_in, const int* in_sizes, int n_in,
                              void* d_out, int out_size, void* d_ws, size_t ws_size,
                              hipStream_t stream) {
    const float* in = (const float*)d_in[0];
    const float* tg = (const float*)d_in[1];
    const float* pw = (const float*)d_in[2];
    float* out = (float*)d_out;
    char* ws = (char*)d_ws;

    unsigned* cnt = (unsigned*)ws;
    double* fredD = (double*)(ws + 64);
    float* pkF = (float*)(ws + 1024);
    unsigned* red = (unsigned*)(ws + 8192);
    unsigned* pk = (unsigned*)(ws + 8192 + 524288);
    const size_t need = 8192 + 524288 + (size_t)NBLK_A * PK_CELLS * sizeof(unsigned);

    if (ws_size >= need) {
        kernA<false><<<NBLK_A, THREADS_A, 0, stream>>>(in, tg, pw, pk, pkF, cnt,
                                                       nullptr, nullptr);
        kernZ<<<NBLK_Z, 1024, 0, stream>>>(pk, pkF, red, fredD, cnt, out);
    } else {
        // fallback: needs only ~37 KB of workspace
        unsigned* gS = (unsigned*)(ws + 4096);
        unsigned* gP = gS + 4096;
        hipMemsetAsync(ws + 4096, 0, 2 * 4096 * sizeof(unsigned), stream);
        kernA<true><<<NBLK_A, THREADS_A, 0, stream>>>(in, tg, pw, nullptr, pkF, nullptr,
                                                      gS, gP);
        kernW<<<1, 1024, 0, stream>>>(gS, gP, pkF, out);
    }
}

// Round 4
// 42.005 us; speedup vs baseline: 1.7915x; 1.7915x over previous
//
#include <hip/hip_runtime.h>

// Problem constants (B=131072 rows, C=64 cols)
#define NROWS 131072
#define NCOLS 64
#define NBLK_A 512
#define THREADS_A 512        // 8 waves per block
#define WAVES_A 8
#define ROWS_PER_WAVE 32     // 512 blocks * 8 waves * 32 rows = 131072
#define PK_CELLS 4096        // packed u16-pair cells per block (2048 S + 2048 P)
#define NGRP 16              // B1 groups (32 source blocks each)

// Workspace layout:
//   [0]       float  pkF[512]             (per-block focal sums, 2 KB)
//   [4096]    u32    red[16][2][64][64]   (512 KB)
//   [528384]  u32    pk[512][4096]        (8 MB)
// need = 8,916,992 B (same footprint class as rounds 2/3, known to fit)

// -------- Kernel A: fused focal loss + Gram (S = t^T t, P = v^T w) --------
// Lane l: cols c4=4*(l&15)..+3, rows row0+h+4q (h=l>>4, q=0..7) via float4.
// ALL 16 float4 loads issued up front (needs ~96 VGPR -> launch_bounds(512,4));
// this is the MLP fix: 16 KB in flight per wave, 256 KB per CU.
// 32-bit column masks built with disjoint bits (4q+h), OR-combined via
// shfl_xor(16|32); lane owns column jc=c4+h (permutation). Each wave runs the
// 64-iter readlane/popc Gram on its own 32-row masks (no cross-wave traffic).
// Byte-packed counts (<=32) -> u16-pair LDS atomics (block max 8*32=256)
// -> per-block packed partial (or global u32 atomics fallback).
template<bool ATOMIC_FLUSH>
__global__ __launch_bounds__(THREADS_A, 4)
void kernA(const float* __restrict__ in, const float* __restrict__ tg,
           const float* __restrict__ pw,
           unsigned* __restrict__ pk, float* __restrict__ pkF,
           unsigned* __restrict__ gS, unsigned* __restrict__ gP) {
    __shared__ unsigned ldsSP[PK_CELLS];   // [0..2047]=S packed, [2048..4095]=P
    __shared__ float fpart[WAVES_A];
    const int tid = threadIdx.x;
#pragma unroll
    for (int k = tid; k < PK_CELLS; k += THREADS_A) ldsSP[k] = 0u;
    __syncthreads();

    const int lane = tid & 63;
    const int wv = tid >> 6;                 // 0..7
    const int h = lane >> 4;                 // row phase 0..3
    const int c4 = (lane & 15) * 4;
    const int jc = c4 + h;                   // this lane's owned column
    const int row0 = blockIdx.x * (WAVES_A * ROWS_PER_WAVE) + wv * ROWS_PER_WAVE;

    const float4 pw4 = *reinterpret_cast<const float4*>(pw + c4);
    const float4* inp = reinterpret_cast<const float4*>(in)
                        + (size_t)(row0 + h) * 16 + (lane & 15);
    const float4* tgp = reinterpret_cast<const float4*>(tg)
                        + (size_t)(row0 + h) * 16 + (lane & 15);

    // ---- issue ALL loads first (MLP = 16 deep) ----
    float4 xr[8], tr[8];
#pragma unroll
    for (int q = 0; q < 8; ++q) xr[q] = inp[(size_t)q * 64];  // stride 4 rows
#pragma unroll
    for (int q = 0; q < 8; ++q) tr[q] = tgp[(size_t)q * 64];

    float fsum = 0.f;
    unsigned m4[4] = {0u, 0u, 0u, 0u};
    unsigned v4[4] = {0u, 0u, 0u, 0u};
    const unsigned hbit = 1u << h;

    auto elem = [&](float x, float t, float pwc, unsigned bq, unsigned& mk, unsigned& vk) {
        float ax = fabsf(x);
        float e = __expf(-ax);                        // exp(-|x|)
        float L = __logf(1.f + e);                    // log1p(exp(-|x|)), stable
        float inv = __builtin_amdgcn_rcpf(1.f + e);   // sigmoid(|x|), ~1ulp
        float qq = e * inv;                           // 1 - sigmoid(|x|)
        bool tb = t > 0.5f;
        bool pb = x >= 0.f;
        float w = (tb == pb) ? qq : inv;              // 1 - p_t
        float bce = tb ? pwc * (L + fmaxf(-x, 0.f)) : (L + fmaxf(x, 0.f));
        fsum += w * w * bce;
        mk |= tb ? bq : 0u;
        vk |= (tb && pb) ? bq : 0u;
    };

#pragma unroll
    for (int q = 0; q < 8; ++q) {            // rows row0 + h + 4q, bit 4q+h
        const unsigned bq = hbit << (4 * q);
        elem(xr[q].x, tr[q].x, pw4.x, bq, m4[0], v4[0]);
        elem(xr[q].y, tr[q].y, pw4.y, bq, m4[1], v4[1]);
        elem(xr[q].z, tr[q].z, pw4.z, bq, m4[2], v4[2]);
        elem(xr[q].w, tr[q].w, pw4.w, bq, m4[3], v4[3]);
    }

    // OR-combine the 4 row-phases; bit b = row row0+b for that column
#pragma unroll
    for (int k = 0; k < 4; ++k) {
        m4[k] |= __shfl_xor(m4[k], 16, 64);
        m4[k] |= __shfl_xor(m4[k], 32, 64);
        v4[k] |= __shfl_xor(v4[k], 16, 64);
        v4[k] |= __shfl_xor(v4[k], 32, 64);
    }
    // lane keeps the mask for its column jc = c4 + h (compile-time selects)
    const unsigned m = (h & 2) ? ((h & 1) ? m4[3] : m4[2]) : ((h & 1) ? m4[1] : m4[0]);
    const unsigned v = (h & 2) ? ((h & 1) ? v4[3] : v4[2]) : ((h & 1) ? v4[1] : v4[0]);
    const unsigned wm = m & ~v;              // t=1 & pred=0

    // Gram: column a lives in lane ri = ((a&3)<<4) | (a>>2)  (inverse of jc(l))
#pragma unroll
    for (int k = 0; k < 16; ++k) {
        unsigned aS = 0u, aP = 0u;
#pragma unroll
        for (int b = 0; b < 4; ++b) {
            const int ri = (b << 4) | k;     // lane owning column a = 4k+b
            unsigned mi = (unsigned)__builtin_amdgcn_readlane((int)m, ri);
            unsigned vi = (unsigned)__builtin_amdgcn_readlane((int)v, ri);
            aS += (unsigned)__popc(mi & m) << (8 * b);    // S[4k+b][jc]
            aP += (unsigned)__popc(vi & wm) << (8 * b);   // P[4k+b][jc]
        }
        atomicAdd(&ldsSP[(2 * k + 0) * 64 + jc],
                  (aS & 0xFFu) | (((aS >> 8) & 0xFFu) << 16));
        atomicAdd(&ldsSP[(2 * k + 1) * 64 + jc],
                  ((aS >> 16) & 0xFFu) | ((aS >> 24) << 16));
        atomicAdd(&ldsSP[2048 + (2 * k + 0) * 64 + jc],
                  (aP & 0xFFu) | (((aP >> 8) & 0xFFu) << 16));
        atomicAdd(&ldsSP[2048 + (2 * k + 1) * 64 + jc],
                  ((aP >> 16) & 0xFFu) | ((aP >> 24) << 16));
    }

    // focal: wave reduce; block reduce after the flush barrier
#pragma unroll
    for (int off = 32; off; off >>= 1) fsum += __shfl_down(fsum, off, 64);
    if (lane == 0) fpart[wv] = fsum;
    __syncthreads();

    if (tid == 0) {
        float tot = 0.f;
#pragma unroll
        for (int k = 0; k < WAVES_A; ++k) tot += fpart[k];
        pkF[blockIdx.x] = tot;
    }

    if (!ATOMIC_FLUSH) {
        uint4* dst4 = reinterpret_cast<uint4*>(pk + (size_t)blockIdx.x * PK_CELLS);
        const uint4* src4 = reinterpret_cast<const uint4*>(ldsSP);
        dst4[tid] = src4[tid];               // 1024 uint4, 2 per thread
        dst4[tid + THREADS_A] = src4[tid + THREADS_A];
    } else {
        for (int k = tid; k < 2048; k += THREADS_A) {
            const int wrd = k >> 6, j = k & 63;
            const int i0 = 2 * wrd;          // word w -> rows 2w, 2w+1
            unsigned s = ldsSP[k], p = ldsSP[2048 + k];
            atomicAdd(&gS[i0 * 64 + j], s & 0xFFFFu);
            atomicAdd(&gS[(i0 + 1) * 64 + j], s >> 16);
            atomicAdd(&gP[i0 * 64 + j], p & 0xFFFFu);
            atomicAdd(&gP[(i0 + 1) * 64 + j], p >> 16);
        }
    }
}

// -------- B1: reduce 512 block-partials into 16 unpacked group sums --------
// Coalesced: consecutive threads read consecutive cells of the same source.
__global__ __launch_bounds__(256)
void kernB1(const unsigned* __restrict__ pk, unsigned* __restrict__ red) {
    const int t = blockIdx.x * 256 + threadIdx.x;  // 0..65535 = 16 grp x 4096
    const int g = t >> 12;
    const int pc = t & 4095;
    unsigned lo = 0u, hi = 0u;
    const unsigned* p = pk + (size_t)(g * 32) * PK_CELLS + pc;
#pragma unroll 8
    for (int b = 0; b < 32; ++b) {
        unsigned w = p[(size_t)b * PK_CELLS];
        lo += w & 0xFFFFu;
        hi += w >> 16;
    }
    const int mat = pc >> 11;                // 0=S, 1=P
    const int e = pc & 2047;
    const int i0 = (e >> 6) * 2;             // word -> rows i0, i0+1
    const int j = e & 63;
    unsigned* o = red + ((size_t)g * 2 + mat) * 4096 + i0 * 64 + j;
    o[0] = lo;
    o[64] = hi;
}

// -------- BC: fused final reduce + penalty + focal + output (1 block) ------
__global__ __launch_bounds__(1024)
void kernBC(const unsigned* __restrict__ red, const float* __restrict__ pkF,
            float* __restrict__ out) {
    const int tid = threadIdx.x;
    double acc = 0.0;
#pragma unroll
    for (int kk = 0; kk < 4; ++kk) {
        const int c = tid + kk * 1024;       // cell (i,j)
        unsigned S = 0u, P = 0u;
#pragma unroll
        for (int g = 0; g < NGRP; ++g) {
            S += red[(size_t)(g * 2 + 0) * 4096 + c];
            P += red[(size_t)(g * 2 + 1) * 4096 + c];
        }
        const int i = c >> 6, j = c & 63;
        const float corr = (float)S * (1.0f / (float)NROWS);
        // penalty_total = 2 * sum A_ij P_ij, A = 0.5*corr thresholded => corr*P
        if (i != j && corr > 0.3f) acc += (double)corr * (double)P;
    }
    if (tid < NBLK_A) acc += (double)pkF[tid];
#pragma unroll
    for (int off = 32; off; off >>= 1) acc += __shfl_down(acc, off, 64);
    __shared__ double wred[16];
    const int lane = tid & 63, wv = tid >> 6;
    if (lane == 0) wred[wv] = acc;
    __syncthreads();
    if (tid < 16) {
        double tot = wred[tid];
#pragma unroll
        for (int off = 8; off; off >>= 1) tot += __shfl_down(tot, off, 64);
        if (tid == 0)
            out[0] = (float)(tot * (1.0 / (double)((size_t)NROWS * NCOLS)));
    }
}

// -------- Fallback finalize (atomic path): one block does everything --------
__global__ __launch_bounds__(1024)
void kernW(const unsigned* __restrict__ gS, const unsigned* __restrict__ gP,
           const float* __restrict__ pkF, float* __restrict__ out) {
    const int tid = threadIdx.x;
    double acc = 0.0;
#pragma unroll
    for (int kk = 0; kk < 4; ++kk) {
        const int c = tid + kk * 1024;
        unsigned S = gS[c], P = gP[c];
        const int i = c >> 6, j = c & 63;
        const float corr = (float)S * (1.0f / (float)NROWS);
        if (i != j && corr > 0.3f) acc += (double)corr * (double)P;
    }
    if (tid < NBLK_A) acc += (double)pkF[tid];
#pragma unroll
    for (int off = 32; off; off >>= 1) acc += __shfl_down(acc, off, 64);
    __shared__ double wred[16];
    const int lane = tid & 63, wv = tid >> 6;
    if (lane == 0) wred[wv] = acc;
    __syncthreads();
    if (tid < 16) {
        double tot = wred[tid];
#pragma unroll
        for (int off = 8; off; off >>= 1) tot += __shfl_down(tot, off, 64);
        if (tid == 0)
            out[0] = (float)(tot * (1.0 / (double)((size_t)NROWS * NCOLS)));
    }
}

extern "C" void kernel_launch(void* const* d_in, const int* in_sizes, int n_in,
                              void* d_out, int out_size, void* d_ws, size_t ws_size,
                              hipStream_t stream) {
    const float* in = (const float*)d_in[0];
    const float* tg = (const float*)d_in[1];
    const float* pw = (const float*)d_in[2];
    float* out = (float*)d_out;
    char* ws = (char*)d_ws;

    float* pkF = (float*)ws;
    unsigned* red = (unsigned*)(ws + 4096);
    unsigned* pk = (unsigned*)(ws + 4096 + 524288);
    const size_t need = 4096 + 524288 + (size_t)NBLK_A * PK_CELLS * sizeof(unsigned);

    if (ws_size >= need) {
        kernA<false><<<NBLK_A, THREADS_A, 0, stream>>>(in, tg, pw, pk, pkF,
                                                       nullptr, nullptr);
        kernB1<<<(NGRP * PK_CELLS) / 256, 256, 0, stream>>>(pk, red);
        kernBC<<<1, 1024, 0, stream>>>(red, pkF, out);
    } else {
        // fallback: needs only ~37 KB of workspace
        unsigned* gS = (unsigned*)(ws + 4096);
        unsigned* gP = gS + 4096;
        hipMemsetAsync(ws + 4096, 0, 2 * 4096 * sizeof(unsigned), stream);
        kernA<true><<<NBLK_A, THREADS_A, 0, stream>>>(in, tg, pw, nullptr, pkF,
                                                      gS, gP);
        kernW<<<1, 1024, 0, stream>>>(gS, gP, pkF, out);
    }
}